// Round 1
// baseline (535.004 us; speedup 1.0000x reference)
//
#include <hip/hip_runtime.h>

#define DH 2048
#define TT 2048
#define BB 4
#define MROWS 8192            // B*T
#define KTOT 6144             // 3*DH
#define NCH 16                // EMA chunks
#define LCH 128               // chunk length
#define POW95_128 0.0014080614f

typedef __attribute__((ext_vector_type(8))) short bf16x8;
typedef __attribute__((ext_vector_type(4))) float f32x4;

__device__ __forceinline__ unsigned short f2bf(float f) {
  union { float f; unsigned int u; } v; v.f = f;
  unsigned int u = v.u;
  return (unsigned short)((u + 0x7FFFu + ((u >> 16) & 1u)) >> 16);
}

__device__ __forceinline__ void gld16(const unsigned short* g, unsigned short* l) {
  __builtin_amdgcn_global_load_lds((const __attribute__((address_space(1))) void*)g,
                                   (__attribute__((address_space(3))) void*)l, 16, 0, 0);
}

// ---------------- W' transpose+convert: Wt[o][kbase+d] = bf16(W[d][o]) ----------------
__global__ __launch_bounds__(256) void prep_w(const float* __restrict__ Wp,
                                              const float* __restrict__ Wi,
                                              const float* __restrict__ Wd,
                                              unsigned short* __restrict__ Wt) {
  __shared__ float tile[64][65];
  int bid = blockIdx.x;                 // 3 * 32 * 32 = 3072
  int mat = bid >> 10;
  int t2 = bid & 1023;
  int dt = (t2 >> 5) * 64;
  int ot = (t2 & 31) * 64;
  const float* W = (mat == 0) ? Wp : ((mat == 1) ? Wi : Wd);
  int kbase = mat * DH;
  int tid = threadIdx.x;
  int r = tid >> 4;
  int c4 = (tid & 15) * 4;
#pragma unroll
  for (int i = 0; i < 4; ++i) {
    int rr = r + i * 16;
    float4 v = *(const float4*)&W[(size_t)(dt + rr) * DH + ot + c4];
    tile[rr][c4 + 0] = v.x; tile[rr][c4 + 1] = v.y;
    tile[rr][c4 + 2] = v.z; tile[rr][c4 + 3] = v.w;
  }
  __syncthreads();
  int o = tid >> 3;                     // 0..31
  int d8 = (tid & 7) * 8;
#pragma unroll
  for (int pass = 0; pass < 2; ++pass) {
    int oo = o + pass * 32;
    union { unsigned short u[8]; uint4 v; } pk;
#pragma unroll
    for (int i = 0; i < 8; ++i) pk.u[i] = f2bf(tile[d8 + i][oo]);
    *(uint4*)&Wt[(size_t)(ot + oo) * KTOT + kbase + dt + d8] = pk.v;
  }
}

// ---------------- kvWd = kick_vec @ Wd (two-stage, deterministic) ----------------
__global__ __launch_bounds__(256) void kv_part_kernel(const float* __restrict__ kick_vec,
                                                      const float* __restrict__ Wd,
                                                      float* __restrict__ part) {
  int blk = blockIdx.x;                 // 128 blocks: 16 d-chunks x 8 o-blocks
  int dchunk = blk >> 3;
  int o = (blk & 7) * 256 + threadIdx.x;
  int d0 = dchunk * 128;
  float s = 0.f;
  for (int i = 0; i < 128; ++i) {
    int d = d0 + i;
    s += kick_vec[d] * Wd[(size_t)d * DH + o];
  }
  part[(size_t)dchunk * DH + o] = s;
}

__global__ __launch_bounds__(256) void kv_reduce_kernel(const float* __restrict__ part,
                                                        float* __restrict__ kvWd) {
  int o = blockIdx.x * 256 + threadIdx.x;
  float s = 0.f;
#pragma unroll
  for (int i = 0; i < 16; ++i) s += part[(size_t)i * DH + o];
  kvWd[o] = s;
}

// ---------------- per-row stats: gates (softmax+clamps+renorm), c = g2*stag*ks ----------------
__global__ __launch_bounds__(256) void rowstats_kernel(const float* __restrict__ x,
                                                       const float* __restrict__ gate_w,
                                                       const float* __restrict__ gate_b,
                                                       const float* __restrict__ kick_w,
                                                       const float* __restrict__ kick_b,
                                                       float* __restrict__ rs) {
  int r = blockIdx.x;                   // 8192
  int t = r & (TT - 1);
  const float* xr = x + (size_t)r * DH;
  const float* xq = xr - DH;
  const bool hp = (t != 0);
  int tid = threadIdx.x;
  float a0 = 0, a1 = 0, a2 = 0, ak = 0, axx = 0, apx = 0, app = 0;
#pragma unroll
  for (int it = 0; it < 2; ++it) {
    int d0 = (tid + it * 256) * 4;
    float4 xv = *(const float4*)(xr + d0);
    float4 pv = hp ? *(const float4*)(xq + d0) : make_float4(0.f, 0.f, 0.f, 0.f);
    float xa[4] = {xv.x, xv.y, xv.z, xv.w};
    float pa[4] = {pv.x, pv.y, pv.z, pv.w};
#pragma unroll
    for (int j = 0; j < 4; ++j) {
      int d = d0 + j;
      float xd = xa[j];
      a0 += xd * gate_w[d * 3 + 0];
      a1 += xd * gate_w[d * 3 + 1];
      a2 += xd * gate_w[d * 3 + 2];
      ak += xd * kick_w[d];
      axx += xd * xd;
      apx += xd * pa[j];
      app += pa[j] * pa[j];
    }
  }
#pragma unroll
  for (int off = 32; off > 0; off >>= 1) {
    a0 += __shfl_xor(a0, off); a1 += __shfl_xor(a1, off);
    a2 += __shfl_xor(a2, off); ak += __shfl_xor(ak, off);
    axx += __shfl_xor(axx, off); apx += __shfl_xor(apx, off);
    app += __shfl_xor(app, off);
  }
  __shared__ float red[4][7];
  int wv = tid >> 6;
  if ((tid & 63) == 0) {
    red[wv][0] = a0; red[wv][1] = a1; red[wv][2] = a2; red[wv][3] = ak;
    red[wv][4] = axx; red[wv][5] = apx; red[wv][6] = app;
  }
  __syncthreads();
  if (tid == 0) {
    float v[7];
#pragma unroll
    for (int i = 0; i < 7; ++i) v[i] = red[0][i] + red[1][i] + red[2][i] + red[3][i];
    float l0 = v[0] + gate_b[0], l1 = v[1] + gate_b[1], l2 = v[2] + gate_b[2];
    float mx = fmaxf(l0, fmaxf(l1, l2));
    float e0 = expf(l0 - mx), e1 = expf(l1 - mx), e2 = expf(l2 - mx);
    float inv = 1.f / (e0 + e1 + e2);
    float G0 = fminf(e0 * inv, 0.6f);
    float G1 = fminf(e1 * inv, 0.6f);
    float G2 = fminf(e2 * inv, 0.6f);
    G1 = fmaxf(G1, 0.25f);
    float inv2 = 1.f / (G0 + G1 + G2);
    G0 *= inv2; G1 *= inv2; G2 *= inv2;
    float ks = 1.f / (1.f + expf(-(v[3] + kick_b[0])));
    float nn = fmaxf(sqrtf(v[4]), 1e-12f) * fmaxf(sqrtf(v[6]), 1e-12f);
    float cs = hp ? (v[5] / nn) : 0.f;
    float cc = (cs > 0.95f) ? (G2 * ks) : 0.f;
    *(float4*)(rs + (size_t)r * 4) = make_float4(G0, G1, G2, cc);
  }
}

// ---------------- EMA pass A: chunk-local scans, store end-carry ----------------
__global__ __launch_bounds__(256) void ema_carry(const float* __restrict__ x,
                                                 float* __restrict__ carry) {
  int gid = blockIdx.x * 256 + threadIdx.x;   // (b, ch, d), 131072 threads
  int d = gid & (DH - 1);
  int ch = (gid >> 11) & (NCH - 1);
  int b = gid >> 15;
  const float* xp = x + ((size_t)b * TT + (size_t)ch * LCH) * DH + d;
  float J;
  if (ch == 0) {
    J = xp[0];
    for (int t = 1; t < LCH; ++t) J = 0.95f * J + 0.05f * xp[(size_t)t * DH];
  } else {
    J = 0.f;
    for (int t = 0; t < LCH; ++t) J = 0.95f * J + 0.05f * xp[(size_t)t * DH];
  }
  carry[gid] = J;
}

// ---------------- EMA pass B: prefix over chunks -> P (carry INTO each chunk) ----------------
__global__ __launch_bounds__(256) void ema_prefix(const float* __restrict__ carry,
                                                  float* __restrict__ P) {
  int gid = blockIdx.x * 256 + threadIdx.x;   // (b, d), 8192 threads
  int d = gid & (DH - 1);
  int b = gid >> 11;
  float run = 0.f;
  for (int ch = 0; ch < NCH; ++ch) {
    size_t idx = ((size_t)b * NCH + ch) * DH + d;
    float cv = carry[idx];
    P[idx] = run;
    run = cv + POW95_128 * run;
  }
}

// ---------------- build A' = [g0*x | g1*I | g2*diff] in bf16 ----------------
__global__ __launch_bounds__(256) void build_a(const float* __restrict__ x,
                                               const float* __restrict__ rs,
                                               const float* __restrict__ P,
                                               unsigned short* __restrict__ A) {
  int gid = blockIdx.x * 256 + threadIdx.x;   // (b, ch, d)
  int d = gid & (DH - 1);
  int ch = (gid >> 11) & (NCH - 1);
  int b = gid >> 15;
  int t0 = ch * LCH;
  const float* xp = x + ((size_t)b * TT + t0) * DH + d;
  unsigned short* Ar = A + ((size_t)b * TT + t0) * KTOT + d;
  float Pv = (ch == 0) ? 0.f : P[((size_t)b * NCH + ch) * DH + d];
  float xprev = (ch == 0) ? 0.f : xp[-(int)DH];
  float J = 0.f, f = 1.f;
  for (int tau = 0; tau < LCH; ++tau) {
    float xv = xp[(size_t)tau * DH];
    int r = b * TT + t0 + tau;
    float4 g = *(const float4*)&rs[(size_t)r * 4];
    if (ch == 0 && tau == 0) J = xv;
    else J = 0.95f * J + 0.05f * xv;
    f *= 0.95f;
    float I = J + f * Pv;
    float diff = (ch == 0 && tau == 0) ? 0.f : (xv - xprev);
    unsigned short* row = Ar + (size_t)tau * KTOT;
    row[0]        = f2bf(g.x * xv);
    row[DH]       = f2bf(g.y * I);
    row[2 * DH]   = f2bf(g.z * diff);
    xprev = xv;
  }
}

// ---------------- fused GEMM: out = A'(8192x6144) @ Wt^T + c*kvWd + bias ----------------
__global__ __launch_bounds__(256) void gemm_kernel(const unsigned short* __restrict__ A,
                                                   const unsigned short* __restrict__ Bt,
                                                   const float* __restrict__ rs,
                                                   const float* __restrict__ kvWd,
                                                   const float* __restrict__ bias,
                                                   float* __restrict__ out) {
  __shared__ __align__(16) unsigned short lA[128 * 64];
  __shared__ __align__(16) unsigned short lB[128 * 64];
  const int tid = threadIdx.x;
  const int wave = tid >> 6, lane = tid & 63;
  const int m0 = blockIdx.y * 128, n0 = blockIdx.x * 128;

  const int srow = wave * 32 + (lane >> 3);
  const int scol = (lane & 7) * 8;
  const unsigned short* ga = A + (size_t)(m0 + srow) * KTOT + scol;
  const unsigned short* gb = Bt + (size_t)(n0 + srow) * KTOT + scol;
  unsigned short* la = &lA[(wave * 32) * 64];
  unsigned short* lb = &lB[(wave * 32) * 64];

  f32x4 acc[4][4] = {};
  const int arow = ((wave >> 1) * 64 + (lane & 15)) * 64;
  const int brow = ((wave & 1) * 64 + (lane & 15)) * 64;
  const int kq = (lane >> 4) * 8;

  for (int k0 = 0; k0 < KTOT; k0 += 64) {
#pragma unroll
    for (int j = 0; j < 4; ++j) {
      gld16(ga + k0 + (size_t)j * 8 * KTOT, la + j * 8 * 64);
      gld16(gb + k0 + (size_t)j * 8 * KTOT, lb + j * 8 * 64);
    }
    __syncthreads();
#pragma unroll
    for (int kb = 0; kb < 2; ++kb) {
      const int kk = kb * 32 + kq;
      bf16x8 av[4], bv[4];
#pragma unroll
      for (int mi = 0; mi < 4; ++mi)
        av[mi] = *(const bf16x8*)&lA[arow + mi * 16 * 64 + kk];
#pragma unroll
      for (int ni = 0; ni < 4; ++ni)
        bv[ni] = *(const bf16x8*)&lB[brow + ni * 16 * 64 + kk];
#pragma unroll
      for (int mi = 0; mi < 4; ++mi)
#pragma unroll
        for (int ni = 0; ni < 4; ++ni)
          acc[mi][ni] = __builtin_amdgcn_mfma_f32_16x16x32_bf16(av[mi], bv[ni], acc[mi][ni], 0, 0, 0);
    }
    __syncthreads();
  }

  const int lr = lane >> 4, lc = lane & 15;
  const int mbase = m0 + (wave >> 1) * 64, nbase = n0 + (wave & 1) * 64;
  float cc[4][4];
#pragma unroll
  for (int mi = 0; mi < 4; ++mi)
#pragma unroll
    for (int rg = 0; rg < 4; ++rg)
      cc[mi][rg] = rs[(size_t)(mbase + mi * 16 + lr * 4 + rg) * 4 + 3];
#pragma unroll
  for (int ni = 0; ni < 4; ++ni) {
    const int n = nbase + ni * 16 + lc;
    const float kv = kvWd[n], bz = bias[n];
#pragma unroll
    for (int mi = 0; mi < 4; ++mi) {
#pragma unroll
      for (int rg = 0; rg < 4; ++rg) {
        const int m = mbase + mi * 16 + lr * 4 + rg;
        out[(size_t)m * DH + n] = acc[mi][ni][rg] + cc[mi][rg] * kv + bz;
      }
    }
  }
}

extern "C" void kernel_launch(void* const* d_in, const int* in_sizes, int n_in,
                              void* d_out, int out_size, void* d_ws, size_t ws_size,
                              hipStream_t stream) {
  const float* x        = (const float*)d_in[0];
  const float* Wp       = (const float*)d_in[1];
  const float* Wi       = (const float*)d_in[2];
  const float* Wd       = (const float*)d_in[3];
  const float* gate_w   = (const float*)d_in[4];
  const float* gate_b   = (const float*)d_in[5];
  const float* kick_vec = (const float*)d_in[6];
  const float* kick_w   = (const float*)d_in[7];
  const float* kick_b   = (const float*)d_in[8];
  const float* bias     = (const float*)d_in[9];
  float* out = (float*)d_out;

  char* ws = (char*)d_ws;
  // workspace layout (bytes)
  unsigned short* Wt   = (unsigned short*)(ws + 0);            // 6144*2048*2  = 25,165,824
  unsigned short* Abuf = (unsigned short*)(ws + 25165824);     // 8192*6144*2  = 100,663,296
  float* rs    = (float*)(ws + 125829120);                     // 8192*4*4     = 131,072
  float* part  = (float*)(ws + 125960192);                     // 16*2048*4    = 131,072
  float* kvWd  = (float*)(ws + 126091264);                     // 2048*4       = 8,192
  float* carry = (float*)(ws + 126099456);                     // 4*16*2048*4  = 524,288
  float* Pbuf  = (float*)(ws + 126623744);                     // 4*16*2048*4  = 524,288
  (void)ws_size; (void)in_sizes; (void)n_in; (void)out_size;

  prep_w<<<dim3(3072), dim3(256), 0, stream>>>(Wp, Wi, Wd, Wt);
  kv_part_kernel<<<dim3(128), dim3(256), 0, stream>>>(kick_vec, Wd, part);
  kv_reduce_kernel<<<dim3(8), dim3(256), 0, stream>>>(part, kvWd);
  rowstats_kernel<<<dim3(8192), dim3(256), 0, stream>>>(x, gate_w, gate_b, kick_w, kick_b, rs);
  ema_carry<<<dim3(512), dim3(256), 0, stream>>>(x, carry);
  ema_prefix<<<dim3(32), dim3(256), 0, stream>>>(carry, Pbuf);
  build_a<<<dim3(512), dim3(256), 0, stream>>>(x, rs, Pbuf, Abuf);
  gemm_kernel<<<dim3(16, 64), dim3(256), 0, stream>>>(Abuf, Wt, rs, kvWd, bias, out);
}

// Round 2
// 444.687 us; speedup vs baseline: 1.2031x; 1.2031x over previous
//
#include <hip/hip_runtime.h>

#define DH 2048
#define TT 2048
#define BB 4
#define MROWS 8192            // B*T
#define KTOT 6144             // 3*DH
#define NCH 64                // EMA chunks
#define LCH 32                // chunk length
#define POW95_L 0.193711483f  // 0.95^32

typedef __attribute__((ext_vector_type(8))) short bf16x8;
typedef __attribute__((ext_vector_type(4))) float f32x4;

__device__ __forceinline__ unsigned short f2bf(float f) {
  union { float f; unsigned int u; } v; v.f = f;
  unsigned int u = v.u;
  return (unsigned short)((u + 0x7FFFu + ((u >> 16) & 1u)) >> 16);
}

__device__ __forceinline__ void gld16(const unsigned short* g, unsigned short* l) {
  __builtin_amdgcn_global_load_lds((const __attribute__((address_space(1))) void*)g,
                                   (__attribute__((address_space(3))) void*)l, 16, 0, 0);
}

// ---------------- W' transpose+convert: Wt[o][kbase+d] = bf16(W[d][o]) ----------------
__global__ __launch_bounds__(256) void prep_w(const float* __restrict__ Wp,
                                              const float* __restrict__ Wi,
                                              const float* __restrict__ Wd,
                                              unsigned short* __restrict__ Wt) {
  __shared__ float tile[64][65];
  int bid = blockIdx.x;                 // 3 * 32 * 32 = 3072
  int mat = bid >> 10;
  int t2 = bid & 1023;
  int dt = (t2 >> 5) * 64;
  int ot = (t2 & 31) * 64;
  const float* W = (mat == 0) ? Wp : ((mat == 1) ? Wi : Wd);
  int kbase = mat * DH;
  int tid = threadIdx.x;
  int r = tid >> 4;
  int c4 = (tid & 15) * 4;
#pragma unroll
  for (int i = 0; i < 4; ++i) {
    int rr = r + i * 16;
    float4 v = *(const float4*)&W[(size_t)(dt + rr) * DH + ot + c4];
    tile[rr][c4 + 0] = v.x; tile[rr][c4 + 1] = v.y;
    tile[rr][c4 + 2] = v.z; tile[rr][c4 + 3] = v.w;
  }
  __syncthreads();
  int o = tid >> 3;                     // 0..31
  int d8 = (tid & 7) * 8;
#pragma unroll
  for (int pass = 0; pass < 2; ++pass) {
    int oo = o + pass * 32;
    union { unsigned short u[8]; uint4 v; } pk;
#pragma unroll
    for (int i = 0; i < 8; ++i) pk.u[i] = f2bf(tile[d8 + i][oo]);
    *(uint4*)&Wt[(size_t)(ot + oo) * KTOT + kbase + dt + d8] = pk.v;
  }
}

// ---------------- kvWd = kick_vec @ Wd (two-stage, deterministic) ----------------
__global__ __launch_bounds__(256) void kv_part_kernel(const float* __restrict__ kick_vec,
                                                      const float* __restrict__ Wd,
                                                      float* __restrict__ part) {
  int blk = blockIdx.x;                 // 128 blocks: 16 d-chunks x 8 o-blocks
  int dchunk = blk >> 3;
  int o = (blk & 7) * 256 + threadIdx.x;
  int d0 = dchunk * 128;
  float s = 0.f;
  for (int i = 0; i < 128; ++i) {
    int d = d0 + i;
    s += kick_vec[d] * Wd[(size_t)d * DH + o];
  }
  part[(size_t)dchunk * DH + o] = s;
}

__global__ __launch_bounds__(256) void kv_reduce_kernel(const float* __restrict__ part,
                                                        float* __restrict__ kvWd) {
  int o = blockIdx.x * 256 + threadIdx.x;
  float s = 0.f;
#pragma unroll
  for (int i = 0; i < 16; ++i) s += part[(size_t)i * DH + o];
  kvWd[o] = s;
}

// ---------------- per-row stats: gates (softmax+clamps+renorm), c = g2*stag*ks ----------------
__global__ __launch_bounds__(256) void rowstats_kernel(const float* __restrict__ x,
                                                       const float* __restrict__ gate_w,
                                                       const float* __restrict__ gate_b,
                                                       const float* __restrict__ kick_w,
                                                       const float* __restrict__ kick_b,
                                                       float* __restrict__ rs) {
  int r = blockIdx.x;                   // 8192
  int t = r & (TT - 1);
  const float* xr = x + (size_t)r * DH;
  const float* xq = xr - DH;
  const bool hp = (t != 0);
  int tid = threadIdx.x;
  float a0 = 0, a1 = 0, a2 = 0, ak = 0, axx = 0, apx = 0, app = 0;
#pragma unroll
  for (int it = 0; it < 2; ++it) {
    int d0 = (tid + it * 256) * 4;
    float4 xv = *(const float4*)(xr + d0);
    float4 pv = hp ? *(const float4*)(xq + d0) : make_float4(0.f, 0.f, 0.f, 0.f);
    // gate_w rows d0..d0+3 = 12 consecutive floats, 16B-aligned (byte off = 48*(d0/4))
    float4 q0 = *(const float4*)(gate_w + (size_t)d0 * 3);
    float4 q1 = *(const float4*)(gate_w + (size_t)d0 * 3 + 4);
    float4 q2 = *(const float4*)(gate_w + (size_t)d0 * 3 + 8);
    float4 kw = *(const float4*)(kick_w + d0);
    float xa[4] = {xv.x, xv.y, xv.z, xv.w};
    float pa[4] = {pv.x, pv.y, pv.z, pv.w};
    a0 += xa[0] * q0.x + xa[1] * q0.w + xa[2] * q1.z + xa[3] * q2.y;
    a1 += xa[0] * q0.y + xa[1] * q1.x + xa[2] * q1.w + xa[3] * q2.z;
    a2 += xa[0] * q0.z + xa[1] * q1.y + xa[2] * q2.x + xa[3] * q2.w;
    ak += xa[0] * kw.x + xa[1] * kw.y + xa[2] * kw.z + xa[3] * kw.w;
#pragma unroll
    for (int j = 0; j < 4; ++j) {
      axx += xa[j] * xa[j];
      apx += xa[j] * pa[j];
      app += pa[j] * pa[j];
    }
  }
#pragma unroll
  for (int off = 32; off > 0; off >>= 1) {
    a0 += __shfl_xor(a0, off); a1 += __shfl_xor(a1, off);
    a2 += __shfl_xor(a2, off); ak += __shfl_xor(ak, off);
    axx += __shfl_xor(axx, off); apx += __shfl_xor(apx, off);
    app += __shfl_xor(app, off);
  }
  __shared__ float red[4][7];
  int wv = tid >> 6;
  if ((tid & 63) == 0) {
    red[wv][0] = a0; red[wv][1] = a1; red[wv][2] = a2; red[wv][3] = ak;
    red[wv][4] = axx; red[wv][5] = apx; red[wv][6] = app;
  }
  __syncthreads();
  if (tid == 0) {
    float v[7];
#pragma unroll
    for (int i = 0; i < 7; ++i) v[i] = red[0][i] + red[1][i] + red[2][i] + red[3][i];
    float l0 = v[0] + gate_b[0], l1 = v[1] + gate_b[1], l2 = v[2] + gate_b[2];
    float mx = fmaxf(l0, fmaxf(l1, l2));
    float e0 = expf(l0 - mx), e1 = expf(l1 - mx), e2 = expf(l2 - mx);
    float inv = 1.f / (e0 + e1 + e2);
    float G0 = fminf(e0 * inv, 0.6f);
    float G1 = fminf(e1 * inv, 0.6f);
    float G2 = fminf(e2 * inv, 0.6f);
    G1 = fmaxf(G1, 0.25f);
    float inv2 = 1.f / (G0 + G1 + G2);
    G0 *= inv2; G1 *= inv2; G2 *= inv2;
    float ks = 1.f / (1.f + expf(-(v[3] + kick_b[0])));
    float nn = fmaxf(sqrtf(v[4]), 1e-12f) * fmaxf(sqrtf(v[6]), 1e-12f);
    float cs = hp ? (v[5] / nn) : 0.f;
    float cc = (cs > 0.95f) ? (G2 * ks) : 0.f;
    *(float4*)(rs + (size_t)r * 4) = make_float4(G0, G1, G2, cc);
  }
}

// ---------------- EMA pass A: chunk-local scans (4 d/thread), store end-carry ----------------
__global__ __launch_bounds__(256) void ema_carry(const float* __restrict__ x,
                                                 float* __restrict__ carry) {
  int gid = blockIdx.x * 256 + threadIdx.x;   // (b, ch, d4): 4*64*512 = 131072 threads
  int d = (gid & 511) * 4;
  int ch = (gid >> 9) & (NCH - 1);
  int b = gid >> 15;
  const float* xp = x + ((size_t)b * TT + (size_t)ch * LCH) * DH + d;
  float J0, J1, J2, J3;
  int tstart;
  if (ch == 0) {
    float4 v = *(const float4*)xp;
    J0 = v.x; J1 = v.y; J2 = v.z; J3 = v.w;
    tstart = 1;
  } else {
    J0 = J1 = J2 = J3 = 0.f;
    tstart = 0;
  }
  for (int t = tstart; t < LCH; ++t) {
    float4 v = *(const float4*)(xp + (size_t)t * DH);
    J0 = 0.95f * J0 + 0.05f * v.x;
    J1 = 0.95f * J1 + 0.05f * v.y;
    J2 = 0.95f * J2 + 0.05f * v.z;
    J3 = 0.95f * J3 + 0.05f * v.w;
  }
  *(float4*)&carry[((size_t)b * NCH + ch) * DH + d] = make_float4(J0, J1, J2, J3);
}

// ---------------- EMA pass B: prefix over chunks -> P (carry INTO each chunk) ----------------
__global__ __launch_bounds__(256) void ema_prefix(const float* __restrict__ carry,
                                                  float* __restrict__ P) {
  int gid = blockIdx.x * 256 + threadIdx.x;   // (b, d4): 2048 threads
  int d = (gid & 511) * 4;
  int b = gid >> 9;
  float4 run = make_float4(0.f, 0.f, 0.f, 0.f);
  for (int ch = 0; ch < NCH; ++ch) {
    size_t idx = ((size_t)b * NCH + ch) * DH + d;
    float4 cv = *(const float4*)&carry[idx];
    *(float4*)&P[idx] = run;
    run.x = cv.x + POW95_L * run.x;
    run.y = cv.y + POW95_L * run.y;
    run.z = cv.z + POW95_L * run.z;
    run.w = cv.w + POW95_L * run.w;
  }
}

// ---------------- build A' = [g0*x | g1*I | g2*diff] in bf16, 8 d/thread ----------------
__global__ __launch_bounds__(256) void build_a(const float* __restrict__ x,
                                               const float* __restrict__ rs,
                                               const float* __restrict__ P,
                                               unsigned short* __restrict__ A) {
  int gid = blockIdx.x * 256 + threadIdx.x;   // (b, ch, d8): 4*64*256 = 65536 threads
  int d = (gid & 255) * 8;
  int ch = (gid >> 8) & (NCH - 1);
  int b = gid >> 14;
  int t0 = ch * LCH;
  const float* xp = x + ((size_t)b * TT + t0) * DH + d;
  unsigned short* Ar = A + ((size_t)b * TT + t0) * KTOT + d;
  float Pv[8], J[8], xprev[8];
  if (ch == 0) {
#pragma unroll
    for (int i = 0; i < 8; ++i) { Pv[i] = 0.f; xprev[i] = 0.f; }
  } else {
    float4 p0 = *(const float4*)&P[((size_t)b * NCH + ch) * DH + d];
    float4 p1 = *(const float4*)&P[((size_t)b * NCH + ch) * DH + d + 4];
    Pv[0] = p0.x; Pv[1] = p0.y; Pv[2] = p0.z; Pv[3] = p0.w;
    Pv[4] = p1.x; Pv[5] = p1.y; Pv[6] = p1.z; Pv[7] = p1.w;
    float4 v0 = *(const float4*)(xp - DH);
    float4 v1 = *(const float4*)(xp - DH + 4);
    xprev[0] = v0.x; xprev[1] = v0.y; xprev[2] = v0.z; xprev[3] = v0.w;
    xprev[4] = v1.x; xprev[5] = v1.y; xprev[6] = v1.z; xprev[7] = v1.w;
  }
#pragma unroll
  for (int i = 0; i < 8; ++i) J[i] = 0.f;
  float f = 1.f;
  const bool first_chunk = (ch == 0);
  for (int tau = 0; tau < LCH; ++tau) {
    float4 v0 = *(const float4*)(xp + (size_t)tau * DH);
    float4 v1 = *(const float4*)(xp + (size_t)tau * DH + 4);
    float xv[8] = {v0.x, v0.y, v0.z, v0.w, v1.x, v1.y, v1.z, v1.w};
    int r = b * TT + t0 + tau;
    float4 g = *(const float4*)&rs[(size_t)r * 4];
    const bool vfirst = first_chunk && (tau == 0);
    f *= 0.95f;
    union { unsigned short u[8]; uint4 v; } op, oi, od;
#pragma unroll
    for (int i = 0; i < 8; ++i) {
      if (vfirst) J[i] = xv[i];
      else J[i] = 0.95f * J[i] + 0.05f * xv[i];
      float I = J[i] + f * Pv[i];
      float diff = vfirst ? 0.f : (xv[i] - xprev[i]);
      op.u[i] = f2bf(g.x * xv[i]);
      oi.u[i] = f2bf(g.y * I);
      od.u[i] = f2bf(g.z * diff);
      xprev[i] = xv[i];
    }
    unsigned short* row = Ar + (size_t)tau * KTOT;
    *(uint4*)(row)          = op.v;
    *(uint4*)(row + DH)     = oi.v;
    *(uint4*)(row + 2 * DH) = od.v;
  }
}

// ---------------- fused GEMM: out = A'(8192x6144) @ Wt^T + c*kvWd + bias ----------------
// XOR-swizzled LDS (col-block ^= row&7) to kill the 16-way bank conflict on
// fragment ds_read_b128; swizzle applied on the GLOBAL source col since
// global_load_lds's LDS dest is fixed at base+lane*16.
__global__ __launch_bounds__(256) void gemm_kernel(const unsigned short* __restrict__ A,
                                                   const unsigned short* __restrict__ Bt,
                                                   const float* __restrict__ rs,
                                                   const float* __restrict__ kvWd,
                                                   const float* __restrict__ bias,
                                                   float* __restrict__ out) {
  __shared__ __align__(16) unsigned short lA[128 * 64];
  __shared__ __align__(16) unsigned short lB[128 * 64];
  const int tid = threadIdx.x;
  const int wave = tid >> 6, lane = tid & 63;
  // XCD-aware swizzle: each XCD (bid%8) owns an 8-mblock slab across all n
  const int bid = blockIdx.x;           // 1024 blocks
  const int xcd = bid & 7;
  const int loc = bid >> 3;             // 0..127
  const int mblk = xcd * 8 + (loc & 7); // 0..63
  const int nblk = loc >> 3;            // 0..15
  const int m0 = mblk * 128, n0 = nblk * 128;

  const int srow = wave * 32 + (lane >> 3);
  const int scol = ((lane & 7) ^ (lane >> 3)) * 8;   // source col-block XOR row&7
  const unsigned short* ga = A + (size_t)(m0 + srow) * KTOT + scol;
  const unsigned short* gb = Bt + (size_t)(n0 + srow) * KTOT + scol;
  unsigned short* la = &lA[(wave * 32) * 64];
  unsigned short* lb = &lB[(wave * 32) * 64];

  f32x4 acc[4][4] = {};
  const int arow = ((wave >> 1) * 64 + (lane & 15)) * 64;
  const int brow = ((wave & 1) * 64 + (lane & 15)) * 64;
  const int cbq = lane >> 4;            // logical col-block within kb (0..3)
  const int swz = lane & 7;             // row&7 of the fragment rows this lane reads

  for (int k0 = 0; k0 < KTOT; k0 += 64) {
#pragma unroll
    for (int j = 0; j < 4; ++j) {
      gld16(ga + k0 + (size_t)j * 8 * KTOT, la + j * 8 * 64);
      gld16(gb + k0 + (size_t)j * 8 * KTOT, lb + j * 8 * 64);
    }
    __syncthreads();
#pragma unroll
    for (int kb = 0; kb < 2; ++kb) {
      const int kphys = ((kb * 4 + cbq) ^ swz) * 8;
      bf16x8 av[4], bv[4];
#pragma unroll
      for (int mi = 0; mi < 4; ++mi)
        av[mi] = *(const bf16x8*)&lA[arow + mi * 16 * 64 + kphys];
#pragma unroll
      for (int ni = 0; ni < 4; ++ni)
        bv[ni] = *(const bf16x8*)&lB[brow + ni * 16 * 64 + kphys];
#pragma unroll
      for (int mi = 0; mi < 4; ++mi)
#pragma unroll
        for (int ni = 0; ni < 4; ++ni)
          acc[mi][ni] = __builtin_amdgcn_mfma_f32_16x16x32_bf16(av[mi], bv[ni], acc[mi][ni], 0, 0, 0);
    }
    __syncthreads();
  }

  const int lr = lane >> 4, lc = lane & 15;
  const int mbase = m0 + (wave >> 1) * 64, nbase = n0 + (wave & 1) * 64;
  float cc[4][4];
#pragma unroll
  for (int mi = 0; mi < 4; ++mi)
#pragma unroll
    for (int rg = 0; rg < 4; ++rg)
      cc[mi][rg] = rs[(size_t)(mbase + mi * 16 + lr * 4 + rg) * 4 + 3];
#pragma unroll
  for (int ni = 0; ni < 4; ++ni) {
    const int n = nbase + ni * 16 + lc;
    const float kv = kvWd[n], bz = bias[n];
#pragma unroll
    for (int mi = 0; mi < 4; ++mi) {
#pragma unroll
      for (int rg = 0; rg < 4; ++rg) {
        const int m = mbase + mi * 16 + lr * 4 + rg;
        out[(size_t)m * DH + n] = acc[mi][ni][rg] + cc[mi][rg] * kv + bz;
      }
    }
  }
}

extern "C" void kernel_launch(void* const* d_in, const int* in_sizes, int n_in,
                              void* d_out, int out_size, void* d_ws, size_t ws_size,
                              hipStream_t stream) {
  const float* x        = (const float*)d_in[0];
  const float* Wp       = (const float*)d_in[1];
  const float* Wi       = (const float*)d_in[2];
  const float* Wd       = (const float*)d_in[3];
  const float* gate_w   = (const float*)d_in[4];
  const float* gate_b   = (const float*)d_in[5];
  const float* kick_vec = (const float*)d_in[6];
  const float* kick_w   = (const float*)d_in[7];
  const float* kick_b   = (const float*)d_in[8];
  const float* bias     = (const float*)d_in[9];
  float* out = (float*)d_out;

  char* ws = (char*)d_ws;
  // workspace layout (bytes)
  unsigned short* Wt   = (unsigned short*)(ws + 0);            // 6144*2048*2  = 25,165,824
  unsigned short* Abuf = (unsigned short*)(ws + 25165824);     // 8192*6144*2  = 100,663,296
  float* rs    = (float*)(ws + 125829120);                     // 8192*4*4     = 131,072
  float* part  = (float*)(ws + 125960192);                     // 16*2048*4    = 131,072
  float* kvWd  = (float*)(ws + 126091264);                     // 2048*4       = 8,192
  float* carry = (float*)(ws + 126099456);                     // 4*64*2048*4  = 2,097,152
  float* Pbuf  = (float*)(ws + 128196608);                     // 4*64*2048*4  = 2,097,152
  (void)ws_size; (void)in_sizes; (void)n_in; (void)out_size;

  prep_w<<<dim3(3072), dim3(256), 0, stream>>>(Wp, Wi, Wd, Wt);
  kv_part_kernel<<<dim3(128), dim3(256), 0, stream>>>(kick_vec, Wd, part);
  kv_reduce_kernel<<<dim3(8), dim3(256), 0, stream>>>(part, kvWd);
  rowstats_kernel<<<dim3(8192), dim3(256), 0, stream>>>(x, gate_w, gate_b, kick_w, kick_b, rs);
  ema_carry<<<dim3(512), dim3(256), 0, stream>>>(x, carry);
  ema_prefix<<<dim3(8), dim3(256), 0, stream>>>(carry, Pbuf);
  build_a<<<dim3(256), dim3(256), 0, stream>>>(x, rs, Pbuf, Abuf);
  gemm_kernel<<<dim3(1024), dim3(256), 0, stream>>>(Abuf, Wt, rs, kvWd, bias, out);
}

// Round 3
// 438.771 us; speedup vs baseline: 1.2193x; 1.0135x over previous
//
#include <hip/hip_runtime.h>

#define DH 2048
#define TT 2048
#define BB 4
#define MROWS 8192            // B*T
#define KTOT 6144             // 3*DH
#define NCH 128               // EMA chunks
#define LCH 16                // chunk length
#define POW95_L 0.44012667f   // 0.95^16

typedef __attribute__((ext_vector_type(8))) short bf16x8;
typedef __attribute__((ext_vector_type(4))) float f32x4;

__device__ __forceinline__ unsigned short f2bf(float f) {
  union { float f; unsigned int u; } v; v.f = f;
  unsigned int u = v.u;
  return (unsigned short)((u + 0x7FFFu + ((u >> 16) & 1u)) >> 16);
}

__device__ __forceinline__ void gld16(const unsigned short* g, unsigned short* l) {
  __builtin_amdgcn_global_load_lds((const __attribute__((address_space(1))) void*)g,
                                   (__attribute__((address_space(3))) void*)l, 16, 0, 0);
}

// ---- W' transpose+convert: Wt[o][kbase+d] = bf16(W[d][o]); fused kvWd partials ----
__global__ __launch_bounds__(256) void prep_w(const float* __restrict__ Wp,
                                              const float* __restrict__ Wi,
                                              const float* __restrict__ Wd,
                                              const float* __restrict__ kick_vec,
                                              unsigned short* __restrict__ Wt,
                                              float* __restrict__ kvWd) {
  __shared__ float tile[64][65];
  int bid = blockIdx.x;                 // 3 * 32 * 32 = 3072
  int mat = bid >> 10;
  int t2 = bid & 1023;
  int dt = (t2 >> 5) * 64;
  int ot = (t2 & 31) * 64;
  const float* W = (mat == 0) ? Wp : ((mat == 1) ? Wi : Wd);
  int kbase = mat * DH;
  int tid = threadIdx.x;
  int r = tid >> 4;
  int c4 = (tid & 15) * 4;
#pragma unroll
  for (int i = 0; i < 4; ++i) {
    int rr = r + i * 16;
    float4 v = *(const float4*)&W[(size_t)(dt + rr) * DH + ot + c4];
    tile[rr][c4 + 0] = v.x; tile[rr][c4 + 1] = v.y;
    tile[rr][c4 + 2] = v.z; tile[rr][c4 + 3] = v.w;
  }
  __syncthreads();
  int o = tid >> 3;                     // 0..31
  int d8 = (tid & 7) * 8;
#pragma unroll
  for (int pass = 0; pass < 2; ++pass) {
    int oo = o + pass * 32;
    union { unsigned short u[8]; uint4 v; } pk;
#pragma unroll
    for (int i = 0; i < 8; ++i) pk.u[i] = f2bf(tile[d8 + i][oo]);
    *(uint4*)&Wt[(size_t)(ot + oo) * KTOT + kbase + dt + d8] = pk.v;
  }
  // kvWd partial for this Wd tile: kvWd[ot+o] += sum_d kick_vec[dt+d]*Wd[d][o]
  if (mat == 2 && tid < 64) {
    float s = 0.f;
#pragma unroll 8
    for (int dd = 0; dd < 64; ++dd) s += kick_vec[dt + dd] * tile[dd][tid];
    atomicAdd(&kvWd[ot + tid], s);
  }
}

// ---- per-row stats: gates (softmax+clamps+renorm), c = g2*stag*ks ----
__global__ __launch_bounds__(256) void rowstats_kernel(const float* __restrict__ x,
                                                       const float* __restrict__ gate_w,
                                                       const float* __restrict__ gate_b,
                                                       const float* __restrict__ kick_w,
                                                       const float* __restrict__ kick_b,
                                                       float* __restrict__ rs) {
  int r = blockIdx.x;                   // 8192
  int t = r & (TT - 1);
  const float* xr = x + (size_t)r * DH;
  const float* xq = xr - DH;
  const bool hp = (t != 0);
  int tid = threadIdx.x;
  float a0 = 0, a1 = 0, a2 = 0, ak = 0, axx = 0, apx = 0, app = 0;
#pragma unroll
  for (int it = 0; it < 2; ++it) {
    int d0 = (tid + it * 256) * 4;
    float4 xv = *(const float4*)(xr + d0);
    float4 pv = hp ? *(const float4*)(xq + d0) : make_float4(0.f, 0.f, 0.f, 0.f);
    float4 q0 = *(const float4*)(gate_w + (size_t)d0 * 3);
    float4 q1 = *(const float4*)(gate_w + (size_t)d0 * 3 + 4);
    float4 q2 = *(const float4*)(gate_w + (size_t)d0 * 3 + 8);
    float4 kw = *(const float4*)(kick_w + d0);
    float xa[4] = {xv.x, xv.y, xv.z, xv.w};
    float pa[4] = {pv.x, pv.y, pv.z, pv.w};
    a0 += xa[0] * q0.x + xa[1] * q0.w + xa[2] * q1.z + xa[3] * q2.y;
    a1 += xa[0] * q0.y + xa[1] * q1.x + xa[2] * q1.w + xa[3] * q2.z;
    a2 += xa[0] * q0.z + xa[1] * q1.y + xa[2] * q2.x + xa[3] * q2.w;
    ak += xa[0] * kw.x + xa[1] * kw.y + xa[2] * kw.z + xa[3] * kw.w;
#pragma unroll
    for (int j = 0; j < 4; ++j) {
      axx += xa[j] * xa[j];
      apx += xa[j] * pa[j];
      app += pa[j] * pa[j];
    }
  }
#pragma unroll
  for (int off = 32; off > 0; off >>= 1) {
    a0 += __shfl_xor(a0, off); a1 += __shfl_xor(a1, off);
    a2 += __shfl_xor(a2, off); ak += __shfl_xor(ak, off);
    axx += __shfl_xor(axx, off); apx += __shfl_xor(apx, off);
    app += __shfl_xor(app, off);
  }
  __shared__ float red[4][7];
  int wv = tid >> 6;
  if ((tid & 63) == 0) {
    red[wv][0] = a0; red[wv][1] = a1; red[wv][2] = a2; red[wv][3] = ak;
    red[wv][4] = axx; red[wv][5] = apx; red[wv][6] = app;
  }
  __syncthreads();
  if (tid == 0) {
    float v[7];
#pragma unroll
    for (int i = 0; i < 7; ++i) v[i] = red[0][i] + red[1][i] + red[2][i] + red[3][i];
    float l0 = v[0] + gate_b[0], l1 = v[1] + gate_b[1], l2 = v[2] + gate_b[2];
    float mx = fmaxf(l0, fmaxf(l1, l2));
    float e0 = expf(l0 - mx), e1 = expf(l1 - mx), e2 = expf(l2 - mx);
    float inv = 1.f / (e0 + e1 + e2);
    float G0 = fminf(e0 * inv, 0.6f);
    float G1 = fminf(e1 * inv, 0.6f);
    float G2 = fminf(e2 * inv, 0.6f);
    G1 = fmaxf(G1, 0.25f);
    float inv2 = 1.f / (G0 + G1 + G2);
    G0 *= inv2; G1 *= inv2; G2 *= inv2;
    float ks = 1.f / (1.f + expf(-(v[3] + kick_b[0])));
    float nn = fmaxf(sqrtf(v[4]), 1e-12f) * fmaxf(sqrtf(v[6]), 1e-12f);
    float cs = hp ? (v[5] / nn) : 0.f;
    float cc = (cs > 0.95f) ? (G2 * ks) : 0.f;
    *(float4*)(rs + (size_t)r * 4) = make_float4(G0, G1, G2, cc);
  }
}

// ---- EMA pass A: chunk-local scans (4 d/thread), store end-carry into cp ----
__global__ __launch_bounds__(256) void ema_carry(const float* __restrict__ x,
                                                 float* __restrict__ cp) {
  int gid = blockIdx.x * 256 + threadIdx.x;   // (b, ch, d4): 4*128*512 = 262144 threads
  int d = (gid & 511) * 4;
  int ch = (gid >> 9) & (NCH - 1);
  int b = gid >> 16;
  const float* xp = x + ((size_t)b * TT + (size_t)ch * LCH) * DH + d;
  float J0, J1, J2, J3;
  int tstart;
  if (ch == 0) {
    float4 v = *(const float4*)xp;
    J0 = v.x; J1 = v.y; J2 = v.z; J3 = v.w;
    tstart = 1;
  } else {
    J0 = J1 = J2 = J3 = 0.f;
    tstart = 0;
  }
#pragma unroll 4
  for (int t = tstart; t < LCH; ++t) {
    float4 v = *(const float4*)(xp + (size_t)t * DH);
    J0 = 0.95f * J0 + 0.05f * v.x;
    J1 = 0.95f * J1 + 0.05f * v.y;
    J2 = 0.95f * J2 + 0.05f * v.z;
    J3 = 0.95f * J3 + 0.05f * v.w;
  }
  *(float4*)&cp[((size_t)b * NCH + ch) * DH + d] = make_float4(J0, J1, J2, J3);
}

// ---- EMA pass B: in-place prefix over chunks: cp[ch] := carry INTO chunk ch ----
__global__ __launch_bounds__(256) void ema_prefix(float* __restrict__ cp) {
  int gid = blockIdx.x * 256 + threadIdx.x;   // (b, d4): 2048 threads
  int d = (gid & 511) * 4;
  int b = gid >> 9;
  float4 run = make_float4(0.f, 0.f, 0.f, 0.f);
  for (int ch = 0; ch < NCH; ++ch) {
    size_t idx = ((size_t)b * NCH + ch) * DH + d;
    float4 cv = *(const float4*)&cp[idx];
    *(float4*)&cp[idx] = run;
    run.x = cv.x + POW95_L * run.x;
    run.y = cv.y + POW95_L * run.y;
    run.z = cv.z + POW95_L * run.z;
    run.w = cv.w + POW95_L * run.w;
  }
}

// ---- build A' = [g0*x | g1*I | g2*diff] in bf16, 8 d/thread, prefetched ----
__global__ __launch_bounds__(256) void build_a(const float* __restrict__ x,
                                               const float* __restrict__ rs,
                                               const float* __restrict__ P,
                                               unsigned short* __restrict__ A) {
  int tid = threadIdx.x;
  int d = tid * 8;
  int ch = blockIdx.x & (NCH - 1);      // 512 blocks: (b, ch)
  int b = blockIdx.x >> 7;
  int t0 = ch * LCH;
  const float* xp = x + ((size_t)b * TT + t0) * DH + d;
  unsigned short* Ar = A + ((size_t)b * TT + t0) * KTOT + d;
  float Pv[8], J[8], xprev[8];
  const bool first_chunk = (ch == 0);
  if (first_chunk) {
#pragma unroll
    for (int i = 0; i < 8; ++i) { Pv[i] = 0.f; xprev[i] = 0.f; }
  } else {
    float4 p0 = *(const float4*)&P[((size_t)b * NCH + ch) * DH + d];
    float4 p1 = *(const float4*)&P[((size_t)b * NCH + ch) * DH + d + 4];
    Pv[0] = p0.x; Pv[1] = p0.y; Pv[2] = p0.z; Pv[3] = p0.w;
    Pv[4] = p1.x; Pv[5] = p1.y; Pv[6] = p1.z; Pv[7] = p1.w;
    float4 v0 = *(const float4*)(xp - DH);
    float4 v1 = *(const float4*)(xp - DH + 4);
    xprev[0] = v0.x; xprev[1] = v0.y; xprev[2] = v0.z; xprev[3] = v0.w;
    xprev[4] = v1.x; xprev[5] = v1.y; xprev[6] = v1.z; xprev[7] = v1.w;
  }
#pragma unroll
  for (int i = 0; i < 8; ++i) J[i] = 0.f;
  float f = 1.f;
  float4 c0 = *(const float4*)(xp);
  float4 c1 = *(const float4*)(xp + 4);
#pragma unroll
  for (int tau = 0; tau < LCH; ++tau) {
    float4 n0, n1;
    if (tau < LCH - 1) {
      n0 = *(const float4*)(xp + (size_t)(tau + 1) * DH);
      n1 = *(const float4*)(xp + (size_t)(tau + 1) * DH + 4);
    }
    float xv[8] = {c0.x, c0.y, c0.z, c0.w, c1.x, c1.y, c1.z, c1.w};
    int r = b * TT + t0 + tau;
    float4 g = *(const float4*)&rs[(size_t)r * 4];
    const bool vfirst = first_chunk && (tau == 0);
    f *= 0.95f;
    union { unsigned short u[8]; uint4 v; } op, oi, od;
#pragma unroll
    for (int i = 0; i < 8; ++i) {
      if (vfirst) J[i] = xv[i];
      else J[i] = 0.95f * J[i] + 0.05f * xv[i];
      float I = J[i] + f * Pv[i];
      float diff = vfirst ? 0.f : (xv[i] - xprev[i]);
      op.u[i] = f2bf(g.x * xv[i]);
      oi.u[i] = f2bf(g.y * I);
      od.u[i] = f2bf(g.z * diff);
      xprev[i] = xv[i];
    }
    unsigned short* row = Ar + (size_t)tau * KTOT;
    *(uint4*)(row)          = op.v;
    *(uint4*)(row + DH)     = oi.v;
    *(uint4*)(row + 2 * DH) = od.v;
    c0 = n0; c1 = n1;
  }
}

// ---- fused GEMM: out = A'(8192x6144) @ Wt^T + c*kvWd + bias (XOR-swizzled LDS) ----
__global__ __launch_bounds__(256) void gemm_kernel(const unsigned short* __restrict__ A,
                                                   const unsigned short* __restrict__ Bt,
                                                   const float* __restrict__ rs,
                                                   const float* __restrict__ kvWd,
                                                   const float* __restrict__ bias,
                                                   float* __restrict__ out) {
  __shared__ __align__(16) unsigned short lA[128 * 64];
  __shared__ __align__(16) unsigned short lB[128 * 64];
  const int tid = threadIdx.x;
  const int wave = tid >> 6, lane = tid & 63;
  const int bid = blockIdx.x;           // 1024 blocks
  const int xcd = bid & 7;
  const int loc = bid >> 3;             // 0..127
  const int mblk = xcd * 8 + (loc & 7); // 0..63
  const int nblk = loc >> 3;            // 0..15
  const int m0 = mblk * 128, n0 = nblk * 128;

  const int srow = wave * 32 + (lane >> 3);
  const int scol = ((lane & 7) ^ (lane >> 3)) * 8;   // source col-block XOR row&7
  const unsigned short* ga = A + (size_t)(m0 + srow) * KTOT + scol;
  const unsigned short* gb = Bt + (size_t)(n0 + srow) * KTOT + scol;
  unsigned short* la = &lA[(wave * 32) * 64];
  unsigned short* lb = &lB[(wave * 32) * 64];

  f32x4 acc[4][4] = {};
  const int arow = ((wave >> 1) * 64 + (lane & 15)) * 64;
  const int brow = ((wave & 1) * 64 + (lane & 15)) * 64;
  const int cbq = lane >> 4;
  const int swz = lane & 7;

  for (int k0 = 0; k0 < KTOT; k0 += 64) {
#pragma unroll
    for (int j = 0; j < 4; ++j) {
      gld16(ga + k0 + (size_t)j * 8 * KTOT, la + j * 8 * 64);
      gld16(gb + k0 + (size_t)j * 8 * KTOT, lb + j * 8 * 64);
    }
    __syncthreads();
#pragma unroll
    for (int kb = 0; kb < 2; ++kb) {
      const int kphys = ((kb * 4 + cbq) ^ swz) * 8;
      bf16x8 av[4], bv[4];
#pragma unroll
      for (int mi = 0; mi < 4; ++mi)
        av[mi] = *(const bf16x8*)&lA[arow + mi * 16 * 64 + kphys];
#pragma unroll
      for (int ni = 0; ni < 4; ++ni)
        bv[ni] = *(const bf16x8*)&lB[brow + ni * 16 * 64 + kphys];
#pragma unroll
      for (int mi = 0; mi < 4; ++mi)
#pragma unroll
        for (int ni = 0; ni < 4; ++ni)
          acc[mi][ni] = __builtin_amdgcn_mfma_f32_16x16x32_bf16(av[mi], bv[ni], acc[mi][ni], 0, 0, 0);
    }
    __syncthreads();
  }

  const int lr = lane >> 4, lc = lane & 15;
  const int mbase = m0 + (wave >> 1) * 64, nbase = n0 + (wave & 1) * 64;
  float cc[4][4];
#pragma unroll
  for (int mi = 0; mi < 4; ++mi)
#pragma unroll
    for (int rg = 0; rg < 4; ++rg)
      cc[mi][rg] = rs[(size_t)(mbase + mi * 16 + lr * 4 + rg) * 4 + 3];
#pragma unroll
  for (int ni = 0; ni < 4; ++ni) {
    const int n = nbase + ni * 16 + lc;
    const float kv = kvWd[n], bz = bias[n];
#pragma unroll
    for (int mi = 0; mi < 4; ++mi) {
#pragma unroll
      for (int rg = 0; rg < 4; ++rg) {
        const int m = mbase + mi * 16 + lr * 4 + rg;
        out[(size_t)m * DH + n] = acc[mi][ni][rg] + cc[mi][rg] * kv + bz;
      }
    }
  }
}

extern "C" void kernel_launch(void* const* d_in, const int* in_sizes, int n_in,
                              void* d_out, int out_size, void* d_ws, size_t ws_size,
                              hipStream_t stream) {
  const float* x        = (const float*)d_in[0];
  const float* Wp       = (const float*)d_in[1];
  const float* Wi       = (const float*)d_in[2];
  const float* Wd       = (const float*)d_in[3];
  const float* gate_w   = (const float*)d_in[4];
  const float* gate_b   = (const float*)d_in[5];
  const float* kick_vec = (const float*)d_in[6];
  const float* kick_w   = (const float*)d_in[7];
  const float* kick_b   = (const float*)d_in[8];
  const float* bias     = (const float*)d_in[9];
  float* out = (float*)d_out;

  char* ws = (char*)d_ws;
  // workspace layout (bytes), total 130,162,688 (<= proven 130,293,760)
  unsigned short* Wt   = (unsigned short*)(ws + 0);            // 6144*2048*2  = 25,165,824
  unsigned short* Abuf = (unsigned short*)(ws + 25165824);     // 8192*6144*2  = 100,663,296
  float* rs    = (float*)(ws + 125829120);                     // 8192*4*4     = 131,072
  float* kvWd  = (float*)(ws + 125960192);                     // 2048*4       = 8,192
  float* cp    = (float*)(ws + 125968384);                     // 4*128*2048*4 = 4,194,304
  (void)ws_size; (void)in_sizes; (void)n_in; (void)out_size;

  hipMemsetAsync(kvWd, 0, DH * sizeof(float), stream);
  prep_w<<<dim3(3072), dim3(256), 0, stream>>>(Wp, Wi, Wd, kick_vec, Wt, kvWd);
  rowstats_kernel<<<dim3(8192), dim3(256), 0, stream>>>(x, gate_w, gate_b, kick_w, kick_b, rs);
  ema_carry<<<dim3(1024), dim3(256), 0, stream>>>(x, cp);
  ema_prefix<<<dim3(8), dim3(256), 0, stream>>>(cp);
  build_a<<<dim3(512), dim3(256), 0, stream>>>(x, rs, cp, Abuf);
  gemm_kernel<<<dim3(1024), dim3(256), 0, stream>>>(Abuf, Wt, rs, kvWd, bias, out);
}

// Round 4
// 430.573 us; speedup vs baseline: 1.2425x; 1.0190x over previous
//
#include <hip/hip_runtime.h>

#define DH 2048               // d_in = d_out = K of GEMM
#define TT 2048
#define BB 4
#define MROWS 8192            // B*T
#define NZ 6144               // GEMM N = 3*DH
#define NCH 128               // scan chunks over T
#define LCH 16                // chunk length
#define LAM 0.44012667f       // 0.95^16
#define LAM2 1.982646e-06f    // 0.95^256

typedef __attribute__((ext_vector_type(8))) short bf16x8;
typedef __attribute__((ext_vector_type(4))) float f32x4;

__device__ __forceinline__ unsigned short f2bf(float f) {
  union { float f; unsigned int u; } v; v.f = f;
  unsigned int u = v.u;
  return (unsigned short)((u + 0x7FFFu + ((u >> 16) & 1u)) >> 16);
}
__device__ __forceinline__ float bf2f(unsigned short u) {
  union { unsigned int i; float f; } v; v.i = ((unsigned int)u) << 16;
  return v.f;
}
__device__ __forceinline__ void gld16(const unsigned short* g, unsigned short* l) {
  __builtin_amdgcn_global_load_lds((const __attribute__((address_space(1))) void*)g,
                                   (__attribute__((address_space(3))) void*)l, 16, 0, 0);
}

// ---- Wt[n][k] = bf16(W[k][o]) with n = mat*2048+o; fused kvWd partials ----
__global__ __launch_bounds__(256) void prep_w(const float* __restrict__ Wp,
                                              const float* __restrict__ Wi,
                                              const float* __restrict__ Wd,
                                              const float* __restrict__ kick_vec,
                                              unsigned short* __restrict__ Wt,
                                              float* __restrict__ kvWd) {
  __shared__ float tile[64][65];
  int bid = blockIdx.x;                 // 3 * 32 * 32 = 3072
  int mat = bid >> 10;
  int t2 = bid & 1023;
  int dt = (t2 >> 5) * 64;
  int ot = (t2 & 31) * 64;
  const float* W = (mat == 0) ? Wp : ((mat == 1) ? Wi : Wd);
  int nbase = mat * DH;
  int tid = threadIdx.x;
  int r = tid >> 4;
  int c4 = (tid & 15) * 4;
#pragma unroll
  for (int i = 0; i < 4; ++i) {
    int rr = r + i * 16;
    float4 v = *(const float4*)&W[(size_t)(dt + rr) * DH + ot + c4];
    tile[rr][c4 + 0] = v.x; tile[rr][c4 + 1] = v.y;
    tile[rr][c4 + 2] = v.z; tile[rr][c4 + 3] = v.w;
  }
  __syncthreads();
  int o = tid >> 3;                     // 0..31
  int d8 = (tid & 7) * 8;
#pragma unroll
  for (int pass = 0; pass < 2; ++pass) {
    int oo = o + pass * 32;
    union { unsigned short u[8]; uint4 v; } pk;
#pragma unroll
    for (int i = 0; i < 8; ++i) pk.u[i] = f2bf(tile[d8 + i][oo]);
    *(uint4*)&Wt[(size_t)(nbase + ot + oo) * DH + dt + d8] = pk.v;
  }
  if (mat == 2 && tid < 64) {
    float s = 0.f;
#pragma unroll 8
    for (int dd = 0; dd < 64; ++dd) s += kick_vec[dt + dd] * tile[dd][tid];
    atomicAdd(&kvWd[ot + tid], s);
  }
}

// ---- fused rowstats + bf16(x) conversion (A staged in d_out) ----
__global__ __launch_bounds__(256) void conv_x(const float* __restrict__ x,
                                              const float* __restrict__ gate_w,
                                              const float* __restrict__ gate_b,
                                              const float* __restrict__ kick_w,
                                              const float* __restrict__ kick_b,
                                              float* __restrict__ rs,
                                              unsigned short* __restrict__ A) {
  int r = blockIdx.x;                   // 8192
  int t = r & (TT - 1);
  const float* xr = x + (size_t)r * DH;
  const float* xq = xr - DH;
  const bool hp = (t != 0);
  int tid = threadIdx.x;
  float a0 = 0, a1 = 0, a2 = 0, ak = 0, axx = 0, apx = 0, app = 0;
#pragma unroll
  for (int it = 0; it < 2; ++it) {
    int d0 = (tid + it * 256) * 4;
    float4 xv = *(const float4*)(xr + d0);
    float4 pv = hp ? *(const float4*)(xq + d0) : make_float4(0.f, 0.f, 0.f, 0.f);
    float4 q0 = *(const float4*)(gate_w + (size_t)d0 * 3);
    float4 q1 = *(const float4*)(gate_w + (size_t)d0 * 3 + 4);
    float4 q2 = *(const float4*)(gate_w + (size_t)d0 * 3 + 8);
    float4 kw = *(const float4*)(kick_w + d0);
    float xa[4] = {xv.x, xv.y, xv.z, xv.w};
    float pa[4] = {pv.x, pv.y, pv.z, pv.w};
    a0 += xa[0] * q0.x + xa[1] * q0.w + xa[2] * q1.z + xa[3] * q2.y;
    a1 += xa[0] * q0.y + xa[1] * q1.x + xa[2] * q1.w + xa[3] * q2.z;
    a2 += xa[0] * q0.z + xa[1] * q1.y + xa[2] * q2.x + xa[3] * q2.w;
    ak += xa[0] * kw.x + xa[1] * kw.y + xa[2] * kw.z + xa[3] * kw.w;
    union { unsigned short u[4]; uint2 v; } pk;
#pragma unroll
    for (int j = 0; j < 4; ++j) {
      axx += xa[j] * xa[j];
      apx += xa[j] * pa[j];
      app += pa[j] * pa[j];
      pk.u[j] = f2bf(xa[j]);
    }
    *(uint2*)&A[(size_t)r * DH + d0] = pk.v;
  }
#pragma unroll
  for (int off = 32; off > 0; off >>= 1) {
    a0 += __shfl_xor(a0, off); a1 += __shfl_xor(a1, off);
    a2 += __shfl_xor(a2, off); ak += __shfl_xor(ak, off);
    axx += __shfl_xor(axx, off); apx += __shfl_xor(apx, off);
    app += __shfl_xor(app, off);
  }
  __shared__ float red[4][7];
  int wv = tid >> 6;
  if ((tid & 63) == 0) {
    red[wv][0] = a0; red[wv][1] = a1; red[wv][2] = a2; red[wv][3] = ak;
    red[wv][4] = axx; red[wv][5] = apx; red[wv][6] = app;
  }
  __syncthreads();
  if (tid == 0) {
    float v[7];
#pragma unroll
    for (int i = 0; i < 7; ++i) v[i] = red[0][i] + red[1][i] + red[2][i] + red[3][i];
    float l0 = v[0] + gate_b[0], l1 = v[1] + gate_b[1], l2 = v[2] + gate_b[2];
    float mx = fmaxf(l0, fmaxf(l1, l2));
    float e0 = expf(l0 - mx), e1 = expf(l1 - mx), e2 = expf(l2 - mx);
    float inv = 1.f / (e0 + e1 + e2);
    float G0 = fminf(e0 * inv, 0.6f);
    float G1 = fminf(e1 * inv, 0.6f);
    float G2 = fminf(e2 * inv, 0.6f);
    G1 = fmaxf(G1, 0.25f);
    float inv2 = 1.f / (G0 + G1 + G2);
    G0 *= inv2; G1 *= inv2; G2 *= inv2;
    float ks = 1.f / (1.f + expf(-(v[3] + kick_b[0])));
    float nn = fmaxf(sqrtf(v[4]), 1e-12f) * fmaxf(sqrtf(v[6]), 1e-12f);
    float cs = hp ? (v[5] / nn) : 0.f;
    float cc = (cs > 0.95f) ? (G2 * ks) : 0.f;
    *(float4*)(rs + (size_t)r * 4) = make_float4(G0, G1, G2, cc);
  }
}

// ---- GEMM: Z(8192x6144, bf16) = A(8192x2048) @ Wt^T (XOR-swizzled LDS) ----
__global__ __launch_bounds__(256) void gemm_kernel(const unsigned short* __restrict__ A,
                                                   const unsigned short* __restrict__ Bt,
                                                   unsigned short* __restrict__ Z) {
  __shared__ __align__(16) unsigned short lA[128 * 64];
  __shared__ __align__(16) unsigned short lB[128 * 64];
  const int tid = threadIdx.x;
  const int wave = tid >> 6, lane = tid & 63;
  const int bid = blockIdx.x;           // 3072 blocks
  const int xcd = bid & 7;
  const int loc = bid >> 3;             // 0..383
  const int mblk = xcd * 8 + (loc & 7); // 0..63
  const int nblk = loc >> 3;            // 0..47
  const int m0 = mblk * 128, n0 = nblk * 128;

  const int srow = wave * 32 + (lane >> 3);
  const int scol = ((lane & 7) ^ (lane >> 3)) * 8;
  const unsigned short* ga = A + (size_t)(m0 + srow) * DH + scol;
  const unsigned short* gb = Bt + (size_t)(n0 + srow) * DH + scol;
  unsigned short* la = &lA[(wave * 32) * 64];
  unsigned short* lb = &lB[(wave * 32) * 64];

  f32x4 acc[4][4] = {};
  const int arow = ((wave >> 1) * 64 + (lane & 15)) * 64;
  const int brow = ((wave & 1) * 64 + (lane & 15)) * 64;
  const int cbq = lane >> 4;
  const int swz = lane & 7;

  for (int k0 = 0; k0 < DH; k0 += 64) {
#pragma unroll
    for (int j = 0; j < 4; ++j) {
      gld16(ga + k0 + (size_t)j * 8 * DH, la + j * 8 * 64);
      gld16(gb + k0 + (size_t)j * 8 * DH, lb + j * 8 * 64);
    }
    __syncthreads();
#pragma unroll
    for (int kb = 0; kb < 2; ++kb) {
      const int kphys = ((kb * 4 + cbq) ^ swz) * 8;
      bf16x8 av[4], bv[4];
#pragma unroll
      for (int mi = 0; mi < 4; ++mi)
        av[mi] = *(const bf16x8*)&lA[arow + mi * 16 * 64 + kphys];
#pragma unroll
      for (int ni = 0; ni < 4; ++ni)
        bv[ni] = *(const bf16x8*)&lB[brow + ni * 16 * 64 + kphys];
#pragma unroll
      for (int mi = 0; mi < 4; ++mi)
#pragma unroll
        for (int ni = 0; ni < 4; ++ni)
          acc[mi][ni] = __builtin_amdgcn_mfma_f32_16x16x32_bf16(av[mi], bv[ni], acc[mi][ni], 0, 0, 0);
    }
    __syncthreads();
  }

  const int lr = lane >> 4, lc = lane & 15;
  const int mbase = m0 + (wave >> 1) * 64, nbase = n0 + (wave & 1) * 64;
#pragma unroll
  for (int ni = 0; ni < 4; ++ni) {
    const int n = nbase + ni * 16 + lc;
#pragma unroll
    for (int mi = 0; mi < 4; ++mi) {
#pragma unroll
      for (int rg = 0; rg < 4; ++rg) {
        const int m = mbase + mi * 16 + lr * 4 + rg;
        Z[(size_t)m * NZ + n] = f2bf(acc[mi][ni][rg]);
      }
    }
  }
}

// ---- chunk-local EMA scan over Z_i, carries to cpb (bf16) ----
__global__ __launch_bounds__(256) void zi_carry(const unsigned short* __restrict__ Z,
                                                unsigned short* __restrict__ cpb) {
  int gid = blockIdx.x * 256 + threadIdx.x;   // (b, ch, n4): 4*128*512 = 262144
  int n = (gid & 511) * 4;
  int ch = (gid >> 9) & (NCH - 1);
  int b = gid >> 16;
  const unsigned short* zp = Z + ((size_t)(b * TT + ch * LCH)) * NZ + DH + n;
  float J0, J1, J2, J3;
  int tstart;
  if (ch == 0) {
    union { unsigned short u[4]; uint2 v; } c;
    c.v = *(const uint2*)zp;
    J0 = bf2f(c.u[0]); J1 = bf2f(c.u[1]); J2 = bf2f(c.u[2]); J3 = bf2f(c.u[3]);
    tstart = 1;
  } else {
    J0 = J1 = J2 = J3 = 0.f;
    tstart = 0;
  }
#pragma unroll 4
  for (int t = tstart; t < LCH; ++t) {
    union { unsigned short u[4]; uint2 v; } c;
    c.v = *(const uint2*)(zp + (size_t)t * NZ);
    J0 = 0.95f * J0 + 0.05f * bf2f(c.u[0]);
    J1 = 0.95f * J1 + 0.05f * bf2f(c.u[1]);
    J2 = 0.95f * J2 + 0.05f * bf2f(c.u[2]);
    J3 = 0.95f * J3 + 0.05f * bf2f(c.u[3]);
  }
  union { unsigned short u[4]; uint2 v; } o;
  o.u[0] = f2bf(J0); o.u[1] = f2bf(J1); o.u[2] = f2bf(J2); o.u[3] = f2bf(J3);
  *(uint2*)&cpb[((size_t)b * NCH + ch) * DH + n] = o.v;
}

// ---- prefix level 1: within-group (16 chunks) relative prefix + group totals ----
__global__ __launch_bounds__(256) void zi_p1(unsigned short* __restrict__ cpb,
                                             float* __restrict__ gc) {
  int gid = blockIdx.x * 256 + threadIdx.x;   // (b, g, n4): 4*8*512 = 16384
  int n = (gid & 511) * 4;
  int g = (gid >> 9) & 7;
  int b = gid >> 12;
  float r0 = 0, r1 = 0, r2 = 0, r3 = 0;
#pragma unroll
  for (int j = 0; j < 16; ++j) {
    size_t idx = ((size_t)b * NCH + g * 16 + j) * DH + n;
    union { unsigned short u[4]; uint2 v; } c;
    c.v = *(const uint2*)&cpb[idx];
    float c0 = bf2f(c.u[0]), c1 = bf2f(c.u[1]), c2 = bf2f(c.u[2]), c3 = bf2f(c.u[3]);
    union { unsigned short u[4]; uint2 v; } o;
    o.u[0] = f2bf(r0); o.u[1] = f2bf(r1); o.u[2] = f2bf(r2); o.u[3] = f2bf(r3);
    *(uint2*)&cpb[idx] = o.v;
    r0 = c0 + LAM * r0; r1 = c1 + LAM * r1;
    r2 = c2 + LAM * r2; r3 = c3 + LAM * r3;
  }
  *(float4*)&gc[((size_t)b * 8 + g) * DH + n] = make_float4(r0, r1, r2, r3);
}

// ---- prefix level 2: scan group totals in place -> carry INTO each group ----
__global__ __launch_bounds__(256) void zi_p2(float* __restrict__ gc) {
  int gid = blockIdx.x * 256 + threadIdx.x;   // (b, n4): 2048
  int n = (gid & 511) * 4;
  int b = gid >> 9;
  float4 run = make_float4(0.f, 0.f, 0.f, 0.f);
#pragma unroll
  for (int g = 0; g < 8; ++g) {
    size_t idx = ((size_t)b * 8 + g) * DH + n;
    float4 old = *(const float4*)&gc[idx];
    *(float4*)&gc[idx] = run;
    run.x = old.x + LAM2 * run.x;
    run.y = old.y + LAM2 * run.y;
    run.z = old.z + LAM2 * run.z;
    run.w = old.w + LAM2 * run.w;
  }
}

// ---- final: out = g0*Zp + g1*EMA(Zi) + g2*(Zd - Zd_prev) + cc*kvWd + bias ----
__global__ __launch_bounds__(256) void final_combine(const unsigned short* __restrict__ Z,
                                                     const float* __restrict__ rs,
                                                     const unsigned short* __restrict__ cpb,
                                                     const float* __restrict__ gc,
                                                     const float* __restrict__ kvWd,
                                                     const float* __restrict__ bias,
                                                     float* __restrict__ out) {
  int tid = threadIdx.x;
  int n = tid * 8;
  int ch = blockIdx.x & (NCH - 1);      // 512 blocks: (b, ch)
  int b = blockIdx.x >> 7;
  int r0 = b * TT + ch * LCH;
  const unsigned short* zb = Z + (size_t)r0 * NZ + n;
  const bool first_chunk = (ch == 0);

  // Pv = cp_rel + lam^j * gP
  int g = ch >> 4, j = ch & 15;
  float pw = 1.f;
  for (int i = 0; i < j; ++i) pw *= LAM;
  float Pv[8];
  {
    union { unsigned short u[8]; uint4 v; } c;
    c.v = *(const uint4*)&cpb[((size_t)b * NCH + ch) * DH + n];
    float4 gp0 = *(const float4*)&gc[((size_t)b * 8 + g) * DH + n];
    float4 gp1 = *(const float4*)&gc[((size_t)b * 8 + g) * DH + n + 4];
    float gp[8] = {gp0.x, gp0.y, gp0.z, gp0.w, gp1.x, gp1.y, gp1.z, gp1.w};
#pragma unroll
    for (int i = 0; i < 8; ++i) Pv[i] = bf2f(c.u[i]) + pw * gp[i];
  }
  float kv[8], bz[8];
  {
    float4 k0 = *(const float4*)&kvWd[n], k1 = *(const float4*)&kvWd[n + 4];
    float4 b0 = *(const float4*)&bias[n], b1 = *(const float4*)&bias[n + 4];
    kv[0]=k0.x; kv[1]=k0.y; kv[2]=k0.z; kv[3]=k0.w; kv[4]=k1.x; kv[5]=k1.y; kv[6]=k1.z; kv[7]=k1.w;
    bz[0]=b0.x; bz[1]=b0.y; bz[2]=b0.z; bz[3]=b0.w; bz[4]=b1.x; bz[5]=b1.y; bz[6]=b1.z; bz[7]=b1.w;
  }
  float zdp[8];
  if (!first_chunk) {
    union { unsigned short u[8]; uint4 v; } c;
    c.v = *(const uint4*)(zb - NZ + 2 * DH);
#pragma unroll
    for (int i = 0; i < 8; ++i) zdp[i] = bf2f(c.u[i]);
  } else {
#pragma unroll
    for (int i = 0; i < 8; ++i) zdp[i] = 0.f;
  }
  float J[8];
#pragma unroll
  for (int i = 0; i < 8; ++i) J[i] = 0.f;
  float f = 1.f;
  uint4 cp = *(const uint4*)(zb);
  uint4 ci = *(const uint4*)(zb + DH);
  uint4 cd = *(const uint4*)(zb + 2 * DH);
#pragma unroll
  for (int tau = 0; tau < LCH; ++tau) {
    uint4 np, ni, nd;
    if (tau < LCH - 1) {
      const unsigned short* zn = zb + (size_t)(tau + 1) * NZ;
      np = *(const uint4*)(zn);
      ni = *(const uint4*)(zn + DH);
      nd = *(const uint4*)(zn + 2 * DH);
    }
    float4 gg = *(const float4*)&rs[(size_t)(r0 + tau) * 4];
    union { unsigned short u[8]; uint4 v; } up, ui, ud;
    up.v = cp; ui.v = ci; ud.v = cd;
    const bool vfirst = first_chunk && (tau == 0);
    f *= 0.95f;
    float o[8];
#pragma unroll
    for (int i = 0; i < 8; ++i) {
      float xp = bf2f(up.u[i]), xi = bf2f(ui.u[i]), xd = bf2f(ud.u[i]);
      if (vfirst) J[i] = xi;
      else J[i] = 0.95f * J[i] + 0.05f * xi;
      float I = J[i] + f * Pv[i];
      float diff = vfirst ? 0.f : (xd - zdp[i]);
      o[i] = gg.x * xp + gg.y * I + gg.z * diff + gg.w * kv[i] + bz[i];
      zdp[i] = xd;
    }
    float* orow = out + (size_t)(r0 + tau) * DH + n;
    *(float4*)(orow) = make_float4(o[0], o[1], o[2], o[3]);
    *(float4*)(orow + 4) = make_float4(o[4], o[5], o[6], o[7]);
    cp = np; ci = ni; cd = nd;
  }
}

extern "C" void kernel_launch(void* const* d_in, const int* in_sizes, int n_in,
                              void* d_out, int out_size, void* d_ws, size_t ws_size,
                              hipStream_t stream) {
  const float* x        = (const float*)d_in[0];
  const float* Wp       = (const float*)d_in[1];
  const float* Wi       = (const float*)d_in[2];
  const float* Wd       = (const float*)d_in[3];
  const float* gate_w   = (const float*)d_in[4];
  const float* gate_b   = (const float*)d_in[5];
  const float* kick_vec = (const float*)d_in[6];
  const float* kick_w   = (const float*)d_in[7];
  const float* kick_b   = (const float*)d_in[8];
  const float* bias     = (const float*)d_in[9];
  float* out = (float*)d_out;

  char* ws = (char*)d_ws;
  // workspace layout (bytes), total 128,327,680 (< proven 130,293,760)
  unsigned short* Wt  = (unsigned short*)(ws + 0);           // 6144*2048*2  = 25,165,824
  unsigned short* Z   = (unsigned short*)(ws + 25165824);    // 8192*6144*2  = 100,663,296
  float* rs   = (float*)(ws + 125829120);                    // 8192*4*4     = 131,072
  float* kvWd = (float*)(ws + 125960192);                    // 2048*4       = 8,192
  unsigned short* cpb = (unsigned short*)(ws + 125968384);   // 4*128*2048*2 = 2,097,152
  float* gc   = (float*)(ws + 128065536);                    // 4*8*2048*4   = 262,144
  // A (bf16 x) staged in d_out: 8192*2048*2 = 33,554,432 <= 67 MB; dead before final writes
  unsigned short* A = (unsigned short*)d_out;
  (void)ws_size; (void)in_sizes; (void)n_in; (void)out_size;

  hipMemsetAsync(kvWd, 0, DH * sizeof(float), stream);
  prep_w<<<dim3(3072), dim3(256), 0, stream>>>(Wp, Wi, Wd, kick_vec, Wt, kvWd);
  conv_x<<<dim3(8192), dim3(256), 0, stream>>>(x, gate_w, gate_b, kick_w, kick_b, rs, A);
  gemm_kernel<<<dim3(3072), dim3(256), 0, stream>>>(A, Wt, Z);
  zi_carry<<<dim3(1024), dim3(256), 0, stream>>>(Z, cpb);
  zi_p1<<<dim3(64), dim3(256), 0, stream>>>(cpb, gc);
  zi_p2<<<dim3(8), dim3(256), 0, stream>>>(gc);
  final_combine<<<dim3(512), dim3(256), 0, stream>>>(Z, rs, cpb, gc, kvWd, bias, out);
}

// Round 5
// 419.837 us; speedup vs baseline: 1.2743x; 1.0256x over previous
//
#include <hip/hip_runtime.h>

#define DH 2048               // d_in = d_out = K of GEMM
#define TT 2048
#define BB 4
#define MROWS 8192            // B*T
#define NZ 6144               // GEMM N = 3*DH
#define NCH 128               // scan chunks over T
#define LCH 16                // chunk length
#define LAM 0.44012667f       // 0.95^16
#define LAM2 1.982646e-06f    // 0.95^256

typedef __attribute__((ext_vector_type(8))) short bf16x8;
typedef __attribute__((ext_vector_type(4))) float f32x4;

__device__ __forceinline__ unsigned short f2bf(float f) {
  union { float f; unsigned int u; } v; v.f = f;
  unsigned int u = v.u;
  return (unsigned short)((u + 0x7FFFu + ((u >> 16) & 1u)) >> 16);
}
__device__ __forceinline__ float bf2f(unsigned short u) {
  union { unsigned int i; float f; } v; v.i = ((unsigned int)u) << 16;
  return v.f;
}
__device__ __forceinline__ void gld16(const unsigned short* g, unsigned short* l) {
  __builtin_amdgcn_global_load_lds((const __attribute__((address_space(1))) void*)g,
                                   (__attribute__((address_space(3))) void*)l, 16, 0, 0);
}

// ---- Wt[n][k] = bf16(W[k][o]) with n = mat*2048+o; fused kvWd partials ----
__global__ __launch_bounds__(256) void prep_w(const float* __restrict__ Wp,
                                              const float* __restrict__ Wi,
                                              const float* __restrict__ Wd,
                                              const float* __restrict__ kick_vec,
                                              unsigned short* __restrict__ Wt,
                                              float* __restrict__ kvWd) {
  __shared__ float tile[64][65];
  int bid = blockIdx.x;                 // 3 * 32 * 32 = 3072
  int mat = bid >> 10;
  int t2 = bid & 1023;
  int dt = (t2 >> 5) * 64;
  int ot = (t2 & 31) * 64;
  const float* W = (mat == 0) ? Wp : ((mat == 1) ? Wi : Wd);
  int nbase = mat * DH;
  int tid = threadIdx.x;
  int r = tid >> 4;
  int c4 = (tid & 15) * 4;
#pragma unroll
  for (int i = 0; i < 4; ++i) {
    int rr = r + i * 16;
    float4 v = *(const float4*)&W[(size_t)(dt + rr) * DH + ot + c4];
    tile[rr][c4 + 0] = v.x; tile[rr][c4 + 1] = v.y;
    tile[rr][c4 + 2] = v.z; tile[rr][c4 + 3] = v.w;
  }
  __syncthreads();
  int o = tid >> 3;                     // 0..31
  int d8 = (tid & 7) * 8;
#pragma unroll
  for (int pass = 0; pass < 2; ++pass) {
    int oo = o + pass * 32;
    union { unsigned short u[8]; uint4 v; } pk;
#pragma unroll
    for (int i = 0; i < 8; ++i) pk.u[i] = f2bf(tile[d8 + i][oo]);
    *(uint4*)&Wt[(size_t)(nbase + ot + oo) * DH + dt + d8] = pk.v;
  }
  if (mat == 2 && tid < 64) {
    float s = 0.f;
#pragma unroll 8
    for (int dd = 0; dd < 64; ++dd) s += kick_vec[dt + dd] * tile[dd][tid];
    atomicAdd(&kvWd[ot + tid], s);
  }
}

// ---- fused rowstats + bf16(x) conversion (A staged in d_out) ----
__global__ __launch_bounds__(256) void conv_x(const float* __restrict__ x,
                                              const float* __restrict__ gate_w,
                                              const float* __restrict__ gate_b,
                                              const float* __restrict__ kick_w,
                                              const float* __restrict__ kick_b,
                                              float* __restrict__ rs,
                                              unsigned short* __restrict__ A) {
  int r = blockIdx.x;                   // 8192
  int t = r & (TT - 1);
  const float* xr = x + (size_t)r * DH;
  const float* xq = xr - DH;
  const bool hp = (t != 0);
  int tid = threadIdx.x;
  float a0 = 0, a1 = 0, a2 = 0, ak = 0, axx = 0, apx = 0, app = 0;
#pragma unroll
  for (int it = 0; it < 2; ++it) {
    int d0 = (tid + it * 256) * 4;
    float4 xv = *(const float4*)(xr + d0);
    float4 pv = hp ? *(const float4*)(xq + d0) : make_float4(0.f, 0.f, 0.f, 0.f);
    float4 q0 = *(const float4*)(gate_w + (size_t)d0 * 3);
    float4 q1 = *(const float4*)(gate_w + (size_t)d0 * 3 + 4);
    float4 q2 = *(const float4*)(gate_w + (size_t)d0 * 3 + 8);
    float4 kw = *(const float4*)(kick_w + d0);
    float xa[4] = {xv.x, xv.y, xv.z, xv.w};
    float pa[4] = {pv.x, pv.y, pv.z, pv.w};
    a0 += xa[0] * q0.x + xa[1] * q0.w + xa[2] * q1.z + xa[3] * q2.y;
    a1 += xa[0] * q0.y + xa[1] * q1.x + xa[2] * q1.w + xa[3] * q2.z;
    a2 += xa[0] * q0.z + xa[1] * q1.y + xa[2] * q2.x + xa[3] * q2.w;
    ak += xa[0] * kw.x + xa[1] * kw.y + xa[2] * kw.z + xa[3] * kw.w;
    union { unsigned short u[4]; uint2 v; } pk;
#pragma unroll
    for (int j = 0; j < 4; ++j) {
      axx += xa[j] * xa[j];
      apx += xa[j] * pa[j];
      app += pa[j] * pa[j];
      pk.u[j] = f2bf(xa[j]);
    }
    *(uint2*)&A[(size_t)r * DH + d0] = pk.v;
  }
#pragma unroll
  for (int off = 32; off > 0; off >>= 1) {
    a0 += __shfl_xor(a0, off); a1 += __shfl_xor(a1, off);
    a2 += __shfl_xor(a2, off); ak += __shfl_xor(ak, off);
    axx += __shfl_xor(axx, off); apx += __shfl_xor(apx, off);
    app += __shfl_xor(app, off);
  }
  __shared__ float red[4][7];
  int wv = tid >> 6;
  if ((tid & 63) == 0) {
    red[wv][0] = a0; red[wv][1] = a1; red[wv][2] = a2; red[wv][3] = ak;
    red[wv][4] = axx; red[wv][5] = apx; red[wv][6] = app;
  }
  __syncthreads();
  if (tid == 0) {
    float v[7];
#pragma unroll
    for (int i = 0; i < 7; ++i) v[i] = red[0][i] + red[1][i] + red[2][i] + red[3][i];
    float l0 = v[0] + gate_b[0], l1 = v[1] + gate_b[1], l2 = v[2] + gate_b[2];
    float mx = fmaxf(l0, fmaxf(l1, l2));
    float e0 = expf(l0 - mx), e1 = expf(l1 - mx), e2 = expf(l2 - mx);
    float inv = 1.f / (e0 + e1 + e2);
    float G0 = fminf(e0 * inv, 0.6f);
    float G1 = fminf(e1 * inv, 0.6f);
    float G2 = fminf(e2 * inv, 0.6f);
    G1 = fmaxf(G1, 0.25f);
    float inv2 = 1.f / (G0 + G1 + G2);
    G0 *= inv2; G1 *= inv2; G2 *= inv2;
    float ks = 1.f / (1.f + expf(-(v[3] + kick_b[0])));
    float nn = fmaxf(sqrtf(v[4]), 1e-12f) * fmaxf(sqrtf(v[6]), 1e-12f);
    float cs = hp ? (v[5] / nn) : 0.f;
    float cc = (cs > 0.95f) ? (G2 * ks) : 0.f;
    *(float4*)(rs + (size_t)r * 4) = make_float4(G0, G1, G2, cc);
  }
}

// ---- GEMM: Z(8192x6144, bf16) = A(8192x2048) @ Wt^T; fused Zi chunk-carry ----
__global__ __launch_bounds__(256) void gemm_kernel(const unsigned short* __restrict__ A,
                                                   const unsigned short* __restrict__ Bt,
                                                   unsigned short* __restrict__ Z,
                                                   unsigned short* __restrict__ cpb) {
  __shared__ __align__(16) unsigned short lA[128 * 64];
  __shared__ __align__(16) unsigned short lB[128 * 64];
  const int tid = threadIdx.x;
  const int wave = tid >> 6, lane = tid & 63;
  const int bid = blockIdx.x;           // 3072 blocks
  const int xcd = bid & 7;
  const int loc = bid >> 3;             // 0..383
  const int mblk = xcd * 8 + (loc & 7); // 0..63
  const int nblk = loc >> 3;            // 0..47
  const int m0 = mblk * 128, n0 = nblk * 128;

  const int srow = wave * 32 + (lane >> 3);
  const int scol = ((lane & 7) ^ (lane >> 3)) * 8;
  const unsigned short* ga = A + (size_t)(m0 + srow) * DH + scol;
  const unsigned short* gb = Bt + (size_t)(n0 + srow) * DH + scol;
  unsigned short* la = &lA[(wave * 32) * 64];
  unsigned short* lb = &lB[(wave * 32) * 64];

  f32x4 acc[4][4] = {};
  const int arow = ((wave >> 1) * 64 + (lane & 15)) * 64;
  const int brow = ((wave & 1) * 64 + (lane & 15)) * 64;
  const int cbq = lane >> 4;
  const int swz = lane & 7;

  for (int k0 = 0; k0 < DH; k0 += 64) {
#pragma unroll
    for (int j = 0; j < 4; ++j) {
      gld16(ga + k0 + (size_t)j * 8 * DH, la + j * 8 * 64);
      gld16(gb + k0 + (size_t)j * 8 * DH, lb + j * 8 * 64);
    }
    __syncthreads();
#pragma unroll
    for (int kb = 0; kb < 2; ++kb) {
      const int kphys = ((kb * 4 + cbq) ^ swz) * 8;
      bf16x8 av[4], bv[4];
#pragma unroll
      for (int mi = 0; mi < 4; ++mi)
        av[mi] = *(const bf16x8*)&lA[arow + mi * 16 * 64 + kphys];
#pragma unroll
      for (int ni = 0; ni < 4; ++ni)
        bv[ni] = *(const bf16x8*)&lB[brow + ni * 16 * 64 + kphys];
#pragma unroll
      for (int mi = 0; mi < 4; ++mi)
#pragma unroll
        for (int ni = 0; ni < 4; ++ni)
          acc[mi][ni] = __builtin_amdgcn_mfma_f32_16x16x32_bf16(av[mi], bv[ni], acc[mi][ni], 0, 0, 0);
    }
    __syncthreads();
  }

  const int lr = lane >> 4, lc = lane & 15;
  const int mbase = m0 + (wave >> 1) * 64, nbase = n0 + (wave & 1) * 64;

  // fused Zi chunk-local EMA carry (replaces zi_carry): chunk == one mi block.
  // carry = sum_idx 0.05*0.95^(15-idx)*Zi[idx], idx = lr*4+rg; first chunk row0 coef = 0.95^15.
  if (nblk >= 16 && nblk < 32) {
    float w12 = (lr == 3) ? 1.0f : (lr == 2) ? 0.81450625f
              : (lr == 1) ? 0.66342043f : 0.54036009f;   // 0.95^(12-4*lr)
    w12 *= 0.05f;
#pragma unroll
    for (int mi = 0; mi < 4; ++mi) {
      const int mrow = mbase + mi * 16;
      const int bb = mrow >> 11;
      const int chh = (mrow >> 4) & (NCH - 1);
      const bool first = (chh == 0);
#pragma unroll
      for (int ni = 0; ni < 4; ++ni) {
        float v0 = acc[mi][ni][0];
        float s = ((v0 * 0.95f + acc[mi][ni][1]) * 0.95f + acc[mi][ni][2]) * 0.95f
                  + acc[mi][ni][3];
        if (first && lr == 0) s += 19.0f * 0.857375f * v0;  // row0 coef -> 0.95^15
        s *= w12;
        s += __shfl_xor(s, 16);
        s += __shfl_xor(s, 32);
        if (lr == 0) {
          int nloc = nbase + ni * 16 + lc - 2048;
          cpb[((size_t)bb * NCH + chh) * DH + nloc] = f2bf(s);
        }
      }
    }
  }

#pragma unroll
  for (int ni = 0; ni < 4; ++ni) {
    const int n = nbase + ni * 16 + lc;
#pragma unroll
    for (int mi = 0; mi < 4; ++mi) {
#pragma unroll
      for (int rg = 0; rg < 4; ++rg) {
        const int m = mbase + mi * 16 + lr * 4 + rg;
        Z[(size_t)m * NZ + n] = f2bf(acc[mi][ni][rg]);
      }
    }
  }
}

// ---- prefix level 1: within-group (16 chunks) relative prefix + group totals ----
__global__ __launch_bounds__(256) void zi_p1(unsigned short* __restrict__ cpb,
                                             float* __restrict__ gc) {
  int gid = blockIdx.x * 256 + threadIdx.x;   // (b, g, n): 4*8*2048 = 65536
  int n = gid & (DH - 1);
  int g = (gid >> 11) & 7;
  int b = gid >> 14;
  float run = 0.f;
#pragma unroll
  for (int j = 0; j < 16; ++j) {
    size_t idx = ((size_t)b * NCH + g * 16 + j) * DH + n;
    float c = bf2f(cpb[idx]);
    cpb[idx] = f2bf(run);
    run = c + LAM * run;
  }
  gc[((size_t)b * 8 + g) * DH + n] = run;
}

// ---- prefix level 2: scan group totals in place -> carry INTO each group ----
__global__ __launch_bounds__(256) void zi_p2(float* __restrict__ gc) {
  int gid = blockIdx.x * 256 + threadIdx.x;   // (b, n): 8192
  int n = gid & (DH - 1);
  int b = gid >> 11;
  float run = 0.f;
#pragma unroll
  for (int g = 0; g < 8; ++g) {
    size_t idx = ((size_t)b * 8 + g) * DH + n;
    float old = gc[idx];
    gc[idx] = run;
    run = old + LAM2 * run;
  }
}

// ---- final: out = g0*Zp + g1*EMA(Zi) + g2*(Zd - Zd_prev) + cc*kvWd + bias ----
__global__ __launch_bounds__(256) void final_combine(const unsigned short* __restrict__ Z,
                                                     const float* __restrict__ rs,
                                                     const unsigned short* __restrict__ cpb,
                                                     const float* __restrict__ gc,
                                                     const float* __restrict__ kvWd,
                                                     const float* __restrict__ bias,
                                                     float* __restrict__ out) {
  int tid = threadIdx.x;
  int n = blockIdx.y * 1024 + tid * 4;  // 4 cols/thread
  int ch = blockIdx.x & (NCH - 1);      // grid (512, 2)
  int b = blockIdx.x >> 7;
  int r0 = b * TT + ch * LCH;
  const unsigned short* zb = Z + (size_t)r0 * NZ + n;
  const bool first_chunk = (ch == 0);

  int g = ch >> 4, j = ch & 15;
  float pw = 1.f;
  for (int i = 0; i < j; ++i) pw *= LAM;
  float Pv[4];
  {
    union { unsigned short u[4]; uint2 v; } c;
    c.v = *(const uint2*)&cpb[((size_t)b * NCH + ch) * DH + n];
    float4 gp = *(const float4*)&gc[((size_t)b * 8 + g) * DH + n];
    float gpa[4] = {gp.x, gp.y, gp.z, gp.w};
#pragma unroll
    for (int i = 0; i < 4; ++i) Pv[i] = bf2f(c.u[i]) + pw * gpa[i];
  }
  float kv[4], bz[4];
  {
    float4 k0 = *(const float4*)&kvWd[n];
    float4 b0 = *(const float4*)&bias[n];
    kv[0]=k0.x; kv[1]=k0.y; kv[2]=k0.z; kv[3]=k0.w;
    bz[0]=b0.x; bz[1]=b0.y; bz[2]=b0.z; bz[3]=b0.w;
  }
  float zdp[4];
  if (!first_chunk) {
    union { unsigned short u[4]; uint2 v; } c;
    c.v = *(const uint2*)(zb - NZ + 2 * DH);
#pragma unroll
    for (int i = 0; i < 4; ++i) zdp[i] = bf2f(c.u[i]);
  } else {
#pragma unroll
    for (int i = 0; i < 4; ++i) zdp[i] = 0.f;
  }
  float J[4];
#pragma unroll
  for (int i = 0; i < 4; ++i) J[i] = 0.f;
  float f = 1.f;
  uint2 cp = *(const uint2*)(zb);
  uint2 ci = *(const uint2*)(zb + DH);
  uint2 cd = *(const uint2*)(zb + 2 * DH);
#pragma unroll
  for (int tau = 0; tau < LCH; ++tau) {
    uint2 np, ni, nd;
    if (tau < LCH - 1) {
      const unsigned short* zn = zb + (size_t)(tau + 1) * NZ;
      np = *(const uint2*)(zn);
      ni = *(const uint2*)(zn + DH);
      nd = *(const uint2*)(zn + 2 * DH);
    }
    float4 gg = *(const float4*)&rs[(size_t)(r0 + tau) * 4];
    union { unsigned short u[4]; uint2 v; } up, ui, ud;
    up.v = cp; ui.v = ci; ud.v = cd;
    const bool vfirst = first_chunk && (tau == 0);
    f *= 0.95f;
    float o[4];
#pragma unroll
    for (int i = 0; i < 4; ++i) {
      float xp = bf2f(up.u[i]), xi = bf2f(ui.u[i]), xd = bf2f(ud.u[i]);
      if (vfirst) J[i] = xi;
      else J[i] = 0.95f * J[i] + 0.05f * xi;
      float I = J[i] + f * Pv[i];
      float diff = vfirst ? 0.f : (xd - zdp[i]);
      o[i] = gg.x * xp + gg.y * I + gg.z * diff + gg.w * kv[i] + bz[i];
      zdp[i] = xd;
    }
    *(float4*)(out + (size_t)(r0 + tau) * DH + n) = make_float4(o[0], o[1], o[2], o[3]);
    cp = np; ci = ni; cd = nd;
  }
}

extern "C" void kernel_launch(void* const* d_in, const int* in_sizes, int n_in,
                              void* d_out, int out_size, void* d_ws, size_t ws_size,
                              hipStream_t stream) {
  const float* x        = (const float*)d_in[0];
  const float* Wp       = (const float*)d_in[1];
  const float* Wi       = (const float*)d_in[2];
  const float* Wd       = (const float*)d_in[3];
  const float* gate_w   = (const float*)d_in[4];
  const float* gate_b   = (const float*)d_in[5];
  const float* kick_vec = (const float*)d_in[6];
  const float* kick_w   = (const float*)d_in[7];
  const float* kick_b   = (const float*)d_in[8];
  const float* bias     = (const float*)d_in[9];
  float* out = (float*)d_out;

  char* ws = (char*)d_ws;
  // workspace layout (bytes), total 128,327,680 (< proven 130,293,760)
  unsigned short* Wt  = (unsigned short*)(ws + 0);           // 6144*2048*2  = 25,165,824
  unsigned short* Z   = (unsigned short*)(ws + 25165824);    // 8192*6144*2  = 100,663,296
  float* rs   = (float*)(ws + 125829120);                    // 8192*4*4     = 131,072
  float* kvWd = (float*)(ws + 125960192);                    // 2048*4       = 8,192
  unsigned short* cpb = (unsigned short*)(ws + 125968384);   // 4*128*2048*2 = 2,097,152
  float* gc   = (float*)(ws + 128065536);                    // 4*8*2048*4   = 262,144
  // A (bf16 x) staged in d_out: 8192*2048*2 = 33,554,432 <= 67 MB; dead before final writes
  unsigned short* A = (unsigned short*)d_out;
  (void)ws_size; (void)in_sizes; (void)n_in; (void)out_size;

  hipMemsetAsync(kvWd, 0, DH * sizeof(float), stream);
  prep_w<<<dim3(3072), dim3(256), 0, stream>>>(Wp, Wi, Wd, kick_vec, Wt, kvWd);
  conv_x<<<dim3(8192), dim3(256), 0, stream>>>(x, gate_w, gate_b, kick_w, kick_b, rs, A);
  gemm_kernel<<<dim3(3072), dim3(256), 0, stream>>>(A, Wt, Z, cpb);
  zi_p1<<<dim3(256), dim3(256), 0, stream>>>(cpb, gc);
  zi_p2<<<dim3(32), dim3(256), 0, stream>>>(gc);
  final_combine<<<dim3(512, 2), dim3(256), 0, stream>>>(Z, rs, cpb, gc, kvWd, bias, out);
}